// Round 2
// baseline (399.287 us; speedup 1.0000x reference)
//
#include <hip/hip_runtime.h>

#define B_ 16
#define K_ 20
#define H_ 256
#define W_ 256
#define HW_ (H_*W_)
#define BK_ (B_*K_)
#define TH_ 32          // output rows per WAVE strip (8 strips/image)
#define KT_ 5           // classes per stats block
#define SCH_ 8          // stats row-chunks (32 rows each)
#define NBLK_FUSED_ (2*K_*B_)   // fused grid = 640 blocks

// ws layout (floats):
//   statsP [SCH_][4][BK_]   : SCH_*4*BK_ = 10240 floats
//   ndP    [640][2]         : 1280 floats
//   cnt    (unsigned, 1)
#define WS_ND_   (SCH_*4*BK_)
#define WS_CNT_  (WS_ND_ + 2*NBLK_FUSED_)

// ---------------------------------------------------------------------------
// stats_k: per-(b,k) sums of labels and labels*inputs_c, written as per-chunk
// partials (no atomics, no pre-zero). Also resets the fused completion counter.
// grid (SCH_, K_/KT_, B_), block 256. float4 loads; inputs reused across KT_.
// ---------------------------------------------------------------------------
__global__ __launch_bounds__(256) void stats_k(const float* __restrict__ labels,
                                               const float* __restrict__ inputs,
                                               float* __restrict__ ws) {
    const int x = threadIdx.x;
    const int chunk = blockIdx.x;   // 0..SCH_-1, 32 rows each
    const int kt = blockIdx.y;      // 0..3
    const int b  = blockIdx.z;
    const int k0 = kt * KT_;
    if (chunk == 0 && kt == 0 && b == 0 && x == 0)
        ((unsigned*)(ws + WS_CNT_))[0] = 0u;   // visible to fused_k (kernel boundary)

    const int cbase = chunk * (32 * W_ / 4);   // float4 units
    const float4* in0 = (const float4*)inputs + (size_t)b * 3 * (HW_/4) + cbase;
    const float4* in1 = in0 + (HW_/4);
    const float4* in2 = in1 + (HW_/4);
    const float4* lb  = (const float4*)labels + (size_t)(b * K_ + k0) * (HW_/4) + cbase;

    float acc[KT_][4];
#pragma unroll
    for (int kk = 0; kk < KT_; ++kk)
        acc[kk][0] = acc[kk][1] = acc[kk][2] = acc[kk][3] = 0.f;

    for (int it = 0; it < 8; ++it) {           // 32 rows * 256 cols / (256 thr * 4)
        const int idx = it * 256 + x;
        const float4 a0 = in0[idx];
        const float4 a1 = in1[idx];
        const float4 a2 = in2[idx];
#pragma unroll
        for (int kk = 0; kk < KT_; ++kk) {
            const float4 l = lb[kk * (HW_/4) + idx];
            acc[kk][0] += (l.x + l.y) + (l.z + l.w);
            acc[kk][1] += fmaf(l.w, a0.w, fmaf(l.z, a0.z, fmaf(l.y, a0.y, l.x * a0.x)));
            acc[kk][2] += fmaf(l.w, a1.w, fmaf(l.z, a1.z, fmaf(l.y, a1.y, l.x * a1.x)));
            acc[kk][3] += fmaf(l.w, a2.w, fmaf(l.z, a2.z, fmaf(l.y, a2.y, l.x * a2.x)));
        }
    }

#pragma unroll
    for (int kk = 0; kk < KT_; ++kk)
#pragma unroll
        for (int q = 0; q < 4; ++q)
            for (int o = 32; o > 0; o >>= 1)
                acc[kk][q] += __shfl_down(acc[kk][q], o);

    __shared__ float sred[4][KT_][4];
    const int widx = x >> 6, lane = x & 63;
    if (lane == 0)
#pragma unroll
        for (int kk = 0; kk < KT_; ++kk)
#pragma unroll
            for (int q = 0; q < 4; ++q) sred[widx][kk][q] = acc[kk][q];
    __syncthreads();
    if (x < KT_ * 4) {
        const int kk = x >> 2, q = x & 3;
        const float v = sred[0][kk][q] + sred[1][kk][q] + sred[2][kk][q] + sred[3][kk][q];
        ws[(chunk * 4 + q) * BK_ + b * K_ + k0 + kk] = v;
    }
}

// ---------------------------------------------------------------------------
// fused_k: one WAVE owns a full 256-col row strip (64 lanes x float4), so the
// horizontal 9-tap halo is one lane's float4 via __shfl -> NO barriers, NO LDS
// in the main loop. Vertical 9-tap via a static mod-8 register ring of
// H-blurred (w, lw). Last block reduces num/den partials and writes the loss.
// grid (2, K_, B_), block 256 = 4 waves = 4 strips of TH_=32 rows.
// ---------------------------------------------------------------------------
__device__ __forceinline__ void hblur(const float* __restrict__ g, float4 v,
                                      int lane, float out[4]) {
    float4 up, dn;
    up.x = __shfl_up(v.x, 1); up.y = __shfl_up(v.y, 1);
    up.z = __shfl_up(v.z, 1); up.w = __shfl_up(v.w, 1);
    dn.x = __shfl_down(v.x, 1); dn.y = __shfl_down(v.y, 1);
    dn.z = __shfl_down(v.z, 1); dn.w = __shfl_down(v.w, 1);
    if (lane == 0)  { up.x = up.y = up.z = up.w = 0.f; }   // image left edge
    if (lane == 63) { dn.x = dn.y = dn.z = dn.w = 0.f; }   // image right edge
    const float t[12] = {up.x, up.y, up.z, up.w, v.x, v.y, v.z, v.w,
                         dn.x, dn.y, dn.z, dn.w};
#pragma unroll
    for (int c = 0; c < 4; ++c) {
        float s = g[0] * t[c];
#pragma unroll
        for (int j = 1; j < 9; ++j) s = fmaf(g[j], t[c + j], s);
        out[c] = s;
    }
}

__global__ __launch_bounds__(256, 4) void fused_k(const float* __restrict__ labels,
                                                  const float* __restrict__ inputs,
                                                  float* __restrict__ ws,
                                                  float* __restrict__ out) {
    const int x = threadIdx.x;
    const int lane = x & 63;
    const int widx = x >> 6;
    const int sg = blockIdx.x;            // 0..1
    const int k = blockIdx.y;
    const int b = blockIdx.z;
    const int bk = b * K_ + k;
    const int r0 = (sg * 4 + widx) * TH_; // this wave's strip

    // ---- class mean from stats partials (uniform per block) ----
    float s0 = 0.f, s1 = 0.f, s2 = 0.f, s3 = 0.f;
#pragma unroll
    for (int c = 0; c < SCH_; ++c) {
        const float* p = ws + c * 4 * BK_;
        s0 += p[bk]; s1 += p[BK_ + bk]; s2 += p[2*BK_ + bk]; s3 += p[3*BK_ + bk];
    }
    const float dn  = s0 + 1e-5f * (float)HW_;
    const float cm0 = s1 / dn, cm1 = s2 / dn, cm2 = s3 / dn;
    const float m2  = cm0*cm0 + cm1*cm1 + cm2*cm2;
    const float tc0 = 2.f*cm0, tc1 = 2.f*cm1, tc2 = 2.f*cm2;

    float g[9];
#pragma unroll
    for (int i = 0; i < 9; ++i) { const float d = (float)(i - 4); g[i] = __expf(-d*d*0.02f); }

    const float4* lb4  = (const float4*)labels + (size_t)bk * (HW_/4);
    const float4* in04 = (const float4*)inputs + (size_t)b * 3 * (HW_/4);
    const float4* in14 = in04 + (HW_/4);
    const float4* in24 = in14 + (HW_/4);

    auto wrow = [&](int gr, float4& w4, float4& lw4) {
        if ((unsigned)gr < (unsigned)H_) {          // wave-uniform branch
            const int i4 = gr * (W_/4) + lane;
            const float4 l  = lb4[i4];
            const float4 a0 = in04[i4];
            const float4 a1 = in14[i4];
            const float4 a2 = in24[i4];
            float d0 = fmaf(a0.x, a0.x - tc0, fmaf(a1.x, a1.x - tc1, fmaf(a2.x, a2.x - tc2, m2)));
            float d1 = fmaf(a0.y, a0.y - tc0, fmaf(a1.y, a1.y - tc1, fmaf(a2.y, a2.y - tc2, m2)));
            float d2 = fmaf(a0.z, a0.z - tc0, fmaf(a1.z, a1.z - tc1, fmaf(a2.z, a2.z - tc2, m2)));
            float d3 = fmaf(a0.w, a0.w - tc0, fmaf(a1.w, a1.w - tc1, fmaf(a2.w, a2.w - tc2, m2)));
            w4.x = __expf(-d0*d0); w4.y = __expf(-d1*d1);
            w4.z = __expf(-d2*d2); w4.w = __expf(-d3*d3);
            lw4.x = l.x*w4.x; lw4.y = l.y*w4.y; lw4.z = l.z*w4.z; lw4.w = l.w*w4.w;
        } else {
            w4.x = w4.y = w4.z = w4.w = 0.f;
            lw4.x = lw4.y = lw4.z = lw4.w = 0.f;
        }
    };

    // ring slot i holds H-blurred row (r0-4+i) initially; slot (rr&7) is
    // replaced by row r0+rr+4 at iteration rr. All indices static after unroll.
    float rhw[8][4], rhlw[8][4];
#pragma unroll
    for (int i = 0; i < 8; ++i) {
        float4 w4, lw4; wrow(r0 - 4 + i, w4, lw4);
        hblur(g, w4,  lane, rhw[i]);
        hblur(g, lw4, lane, rhlw[i]);
    }

    float num = 0.f, den = 0.f;
#pragma unroll 1
    for (int ro = 0; ro < TH_ / 8; ++ro) {
#pragma unroll
        for (int u = 0; u < 8; ++u) {
            const int orow = r0 + ro * 8 + u;
            const float4 lc = lb4[orow * (W_/4) + lane];   // always in-bounds
            float4 w4, lw4; wrow(orow + 4, w4, lw4);
            float chw[4], chlw[4];
            hblur(g, w4,  lane, chw);
            hblur(g, lw4, lane, chlw);
            float vw[4], vlw[4];
#pragma unroll
            for (int c = 0; c < 4; ++c) { vw[c] = g[8]*chw[c]; vlw[c] = g[8]*chlw[c]; }
#pragma unroll
            for (int j = 0; j < 8; ++j) {
                const int s = (u + j) & 7;                 // static
#pragma unroll
                for (int c = 0; c < 4; ++c) {
                    vw[c]  = fmaf(g[j], rhw[s][c],  vw[c]);
                    vlw[c] = fmaf(g[j], rhlw[s][c], vlw[c]);
                }
            }
            num = fmaf(lc.x, vlw[0], fmaf(lc.y, vlw[1], fmaf(lc.z, vlw[2], fmaf(lc.w, vlw[3], num))));
            den = fmaf(lc.x, vw[0],  fmaf(lc.y, vw[1],  fmaf(lc.z, vw[2],  fmaf(lc.w, vw[3],  den))));
#pragma unroll
            for (int c = 0; c < 4; ++c) { rhw[u][c] = chw[c]; rhlw[u][c] = chlw[c]; }
        }
    }

    // ---- block reduce + last-block finalize ----
    for (int o = 32; o > 0; o >>= 1) { num += __shfl_down(num, o); den += __shfl_down(den, o); }
    __shared__ float rb[4][2];
    __shared__ unsigned sdone;
    if (lane == 0) { rb[widx][0] = num; rb[widx][1] = den; }
    __syncthreads();
    if (x == 0) {
        const float fn = rb[0][0] + rb[1][0] + rb[2][0] + rb[3][0];
        const float fd = rb[0][1] + rb[1][1] + rb[2][1] + rb[3][1];
        const int nd_idx = k * 32 + b * 2 + sg;            // group by class
        float2* nd2 = (float2*)(ws + WS_ND_);
        nd2[nd_idx] = make_float2(fn, fd);
        __threadfence();                                    // release partial
        sdone = atomicAdd((unsigned*)(ws + WS_CNT_), 1u);
    }
    __syncthreads();
    if (sdone == (unsigned)(NBLK_FUSED_ - 1)) {            // last block finalizes
        __threadfence();                                    // acquire partials
        if (x < 64) {
            float term = 0.f;
            if (x < K_) {
                const float2* nd2 = (const float2*)(ws + WS_ND_);
                float ns = 0.f, ds = 0.f;
                for (int i = 0; i < 32; ++i) {
                    const float2 v = nd2[x * 32 + i];
                    ns += v.x; ds += v.y;
                }
                term = fabsf(ns / (ds + 1e-6f));
            }
            for (int o = 32; o > 0; o >>= 1) term += __shfl_down(term, o);
            if (x == 0) out[0] = (float)K_ - term;
        }
    }
}

extern "C" void kernel_launch(void* const* d_in, const int* in_sizes, int n_in,
                              void* d_out, int out_size, void* d_ws, size_t ws_size,
                              hipStream_t stream) {
    const float* labels = (const float*)d_in[0];
    const float* inputs = (const float*)d_in[1];
    float* ws = (float*)d_ws;   // needs (SCH_*4*BK_ + 2*640 + 1) floats ~= 46 KB

    stats_k<<<dim3(SCH_, K_ / KT_, B_), 256, 0, stream>>>(labels, inputs, ws);
    fused_k<<<dim3(2, K_, B_), 256, 0, stream>>>(labels, inputs, ws, (float*)d_out);
}

// Round 3
// 254.369 us; speedup vs baseline: 1.5697x; 1.5697x over previous
//
#include <hip/hip_runtime.h>

#define B_ 16
#define K_ 20
#define H_ 256
#define W_ 256
#define HW_ (H_*W_)
#define BK_ (B_*K_)
#define TH_ 16          // output rows per WAVE strip (16 strips/image)
#define KT_ 5           // classes per stats block
#define SCH_ 4          // stats row-chunks (64 rows each)
#define NBLK_FUSED_ (4*K_*B_)   // fused grid = 1280 blocks

// ws layout (floats): statsP [SCH_][4][BK_] | ndP [NBLK][2] | cnt
#define WS_ND_   (SCH_*4*BK_)
#define WS_CNT_  (WS_ND_ + 2*NBLK_FUSED_)

// Gaussian taps exp(-d^2/50), d=1..4 (tap symmetry: 4 distinct + center 1.0)
#define G1T 0.980198673f   // d=1
#define G2T 0.923116346f   // d=2
#define G3T 0.835270211f   // d=3
#define G4T 0.726149037f   // d=4

// ---------------------------------------------------------------------------
// stats_k: per-(b,k) sums of labels and labels*inputs_c as per-chunk partials
// (no atomics, no pre-zero). Also resets the fused completion counter.
// grid (SCH_, K_/KT_, B_), block 256. float4 loads; inputs reused across KT_.
// ---------------------------------------------------------------------------
__global__ __launch_bounds__(256) void stats_k(const float* __restrict__ labels,
                                               const float* __restrict__ inputs,
                                               float* __restrict__ ws) {
    const int x = threadIdx.x;
    const int chunk = blockIdx.x;   // 0..SCH_-1, 64 rows each
    const int kt = blockIdx.y;      // 0..3
    const int b  = blockIdx.z;
    const int k0 = kt * KT_;
    if (chunk == 0 && kt == 0 && b == 0 && x == 0)
        ((unsigned*)(ws + WS_CNT_))[0] = 0u;   // visible to fused_k (kernel boundary)

    const int cbase = chunk * (64 * W_ / 4);   // float4 units
    const float4* in0 = (const float4*)inputs + (size_t)b * 3 * (HW_/4) + cbase;
    const float4* in1 = in0 + (HW_/4);
    const float4* in2 = in1 + (HW_/4);
    const float4* lb  = (const float4*)labels + (size_t)(b * K_ + k0) * (HW_/4) + cbase;

    float acc[KT_][4];
#pragma unroll
    for (int kk = 0; kk < KT_; ++kk)
        acc[kk][0] = acc[kk][1] = acc[kk][2] = acc[kk][3] = 0.f;

    for (int it = 0; it < 16; ++it) {          // 64 rows * 256 cols / (256 thr * 4)
        const int idx = it * 256 + x;
        const float4 a0 = in0[idx];
        const float4 a1 = in1[idx];
        const float4 a2 = in2[idx];
#pragma unroll
        for (int kk = 0; kk < KT_; ++kk) {
            const float4 l = lb[kk * (HW_/4) + idx];
            acc[kk][0] += (l.x + l.y) + (l.z + l.w);
            acc[kk][1] += fmaf(l.w, a0.w, fmaf(l.z, a0.z, fmaf(l.y, a0.y, l.x * a0.x)));
            acc[kk][2] += fmaf(l.w, a1.w, fmaf(l.z, a1.z, fmaf(l.y, a1.y, l.x * a1.x)));
            acc[kk][3] += fmaf(l.w, a2.w, fmaf(l.z, a2.z, fmaf(l.y, a2.y, l.x * a2.x)));
        }
    }

#pragma unroll
    for (int kk = 0; kk < KT_; ++kk)
#pragma unroll
        for (int q = 0; q < 4; ++q)
            for (int o = 32; o > 0; o >>= 1)
                acc[kk][q] += __shfl_down(acc[kk][q], o);

    __shared__ float sred[4][KT_][4];
    const int widx = x >> 6, lane = x & 63;
    if (lane == 0)
#pragma unroll
        for (int kk = 0; kk < KT_; ++kk)
#pragma unroll
            for (int q = 0; q < 4; ++q) sred[widx][kk][q] = acc[kk][q];
    __syncthreads();
    if (x < KT_ * 4) {
        const int kk = x >> 2, q = x & 3;
        const float v = sred[0][kk][q] + sred[1][kk][q] + sred[2][kk][q] + sred[3][kk][q];
        ws[(chunk * 4 + q) * BK_ + b * K_ + k0 + kk] = v;
    }
}

// ---------------------------------------------------------------------------
// hblur4: 9-tap horizontal blur of a wave-wide row (64 lanes x float4).
// Halo = one lane's float4 via shfl. Symmetric-pair form, 4 SGPR constants.
// ---------------------------------------------------------------------------
__device__ __forceinline__ void hblur4(const float4 v, const int lane, float o[4]) {
    float u0 = __shfl_up(v.x, 1), u1 = __shfl_up(v.y, 1);
    float u2 = __shfl_up(v.z, 1), u3 = __shfl_up(v.w, 1);
    float d0 = __shfl_down(v.x, 1), d1 = __shfl_down(v.y, 1);
    float d2 = __shfl_down(v.z, 1), d3 = __shfl_down(v.w, 1);
    if (lane == 0)  { u0 = u1 = u2 = u3 = 0.f; }   // image left edge (zero pad)
    if (lane == 63) { d0 = d1 = d2 = d3 = 0.f; }   // image right edge
    // t[0..11] = u0..3, v.x..w, d0..3 ; o[c] = sum_j g[j]*t[c+j]
    o[0] = fmaf(G4T, u0 + d0, fmaf(G3T, u1 + v.w, fmaf(G2T, u2 + v.z, fmaf(G1T, u3 + v.y, v.x))));
    o[1] = fmaf(G4T, u1 + d1, fmaf(G3T, u2 + d0,  fmaf(G2T, u3 + v.w, fmaf(G1T, v.x + v.z, v.y))));
    o[2] = fmaf(G4T, u2 + d2, fmaf(G3T, u3 + d1,  fmaf(G2T, v.x + d0, fmaf(G1T, v.y + v.w, v.z))));
    o[3] = fmaf(G4T, u3 + d3, fmaf(G3T, v.x + d2, fmaf(G2T, v.y + d1, fmaf(G1T, v.z + d0,  v.w))));
}

// ---------------------------------------------------------------------------
// fused_k: one WAVE owns a full 256-col row strip (64 lanes x float4); the
// horizontal halo is intra-wave shfl -> NO barriers, NO LDS in the main loop.
// Vertical 9-tap via static mod-8 register ring of H-blurred (w, lw).
// Vertical sum fused straight into num/den (no intermediate arrays).
// grid (4, K_, B_), block 256 = 4 waves = 4 strips of TH_=16 rows.
// NO min-occupancy clause: round-2's (256,4) forced the ring to scratch
// (583 MB WRITE_SIZE). Let the allocator take ~150-180 VGPRs instead.
// ---------------------------------------------------------------------------
__global__ __launch_bounds__(256) void fused_k(const float* __restrict__ labels,
                                               const float* __restrict__ inputs,
                                               float* __restrict__ ws,
                                               float* __restrict__ out) {
    const int x = threadIdx.x;
    const int lane = x & 63;
    const int widx = x >> 6;
    const int sg = blockIdx.x;            // 0..3
    const int k = blockIdx.y;
    const int b = blockIdx.z;
    const int bk = b * K_ + k;
    const int r0 = (sg * 4 + widx) * TH_; // this wave's strip

    // ---- class mean from stats partials (uniform per block) ----
    float s0 = 0.f, s1 = 0.f, s2 = 0.f, s3 = 0.f;
#pragma unroll
    for (int c = 0; c < SCH_; ++c) {
        const float* p = ws + c * 4 * BK_;
        s0 += p[bk]; s1 += p[BK_ + bk]; s2 += p[2*BK_ + bk]; s3 += p[3*BK_ + bk];
    }
    const float dn  = s0 + 1e-5f * (float)HW_;
    const float cm0 = s1 / dn, cm1 = s2 / dn, cm2 = s3 / dn;
    const float m2  = cm0*cm0 + cm1*cm1 + cm2*cm2;
    const float tc0 = 2.f*cm0, tc1 = 2.f*cm1, tc2 = 2.f*cm2;

    const float4* lb4  = (const float4*)labels + (size_t)bk * (HW_/4);
    const float4* in04 = (const float4*)inputs + (size_t)b * 3 * (HW_/4);
    const float4* in14 = in04 + (HW_/4);
    const float4* in24 = in14 + (HW_/4);

    auto wrow = [&](int gr, float4& w4, float4& lw4) {
        if ((unsigned)gr < (unsigned)H_) {          // wave-uniform branch
            const int i4 = gr * (W_/4) + lane;
            const float4 l  = lb4[i4];
            const float4 a0 = in04[i4];
            const float4 a1 = in14[i4];
            const float4 a2 = in24[i4];
            const float d0 = fmaf(a0.x, a0.x - tc0, fmaf(a1.x, a1.x - tc1, fmaf(a2.x, a2.x - tc2, m2)));
            const float d1 = fmaf(a0.y, a0.y - tc0, fmaf(a1.y, a1.y - tc1, fmaf(a2.y, a2.y - tc2, m2)));
            const float d2 = fmaf(a0.z, a0.z - tc0, fmaf(a1.z, a1.z - tc1, fmaf(a2.z, a2.z - tc2, m2)));
            const float d3 = fmaf(a0.w, a0.w - tc0, fmaf(a1.w, a1.w - tc1, fmaf(a2.w, a2.w - tc2, m2)));
            w4.x = __expf(-d0*d0); w4.y = __expf(-d1*d1);
            w4.z = __expf(-d2*d2); w4.w = __expf(-d3*d3);
            lw4.x = l.x*w4.x; lw4.y = l.y*w4.y; lw4.z = l.z*w4.z; lw4.w = l.w*w4.w;
        } else {
            w4 = make_float4(0.f, 0.f, 0.f, 0.f);
            lw4 = make_float4(0.f, 0.f, 0.f, 0.f);
        }
    };

    // ring slot i holds H-blurred row (r0-4+i); at iter rr, row r0+rr-4+j is
    // in slot (rr+j)&7, and slot (rr&7) is replaced by row r0+rr+4 afterwards.
    float rhw[8][4], rhlw[8][4];
#pragma unroll
    for (int i = 0; i < 8; ++i) {
        float4 w4, lw4; wrow(r0 - 4 + i, w4, lw4);
        hblur4(w4,  lane, rhw[i]);
        hblur4(lw4, lane, rhlw[i]);
    }

    float num = 0.f, den = 0.f;
#pragma unroll 1
    for (int ro = 0; ro < TH_ / 8; ++ro) {
#pragma unroll
        for (int u = 0; u < 8; ++u) {
            const int orow = r0 + ro * 8 + u;
            float4 w4, lw4; wrow(orow + 4, w4, lw4);
            float cw[4], clw[4];
            hblur4(w4,  lane, cw);
            hblur4(lw4, lane, clw);
            const float4 lc = lb4[orow * (W_/4) + lane];   // always in-bounds
            const float lca[4] = {lc.x, lc.y, lc.z, lc.w};
            // vertical 9-tap (symmetric pairs), fused into num/den
            const int s0i = u, s1i = (u+1)&7, s2i = (u+2)&7, s3i = (u+3)&7;
            const int s4i = (u+4)&7, s5i = (u+5)&7, s6i = (u+6)&7, s7i = (u+7)&7;
#pragma unroll
            for (int c = 0; c < 4; ++c) {
                const float vw = fmaf(G4T, rhw[s0i][c] + cw[c],
                                 fmaf(G3T, rhw[s1i][c] + rhw[s7i][c],
                                 fmaf(G2T, rhw[s2i][c] + rhw[s6i][c],
                                 fmaf(G1T, rhw[s3i][c] + rhw[s5i][c], rhw[s4i][c]))));
                const float vl = fmaf(G4T, rhlw[s0i][c] + clw[c],
                                 fmaf(G3T, rhlw[s1i][c] + rhlw[s7i][c],
                                 fmaf(G2T, rhlw[s2i][c] + rhlw[s6i][c],
                                 fmaf(G1T, rhlw[s3i][c] + rhlw[s5i][c], rhlw[s4i][c]))));
                num = fmaf(lca[c], vl, num);
                den = fmaf(lca[c], vw, den);
            }
#pragma unroll
            for (int c = 0; c < 4; ++c) { rhw[u][c] = cw[c]; rhlw[u][c] = clw[c]; }
        }
    }

    // ---- block reduce + last-block finalize ----
    for (int o = 32; o > 0; o >>= 1) { num += __shfl_down(num, o); den += __shfl_down(den, o); }
    __shared__ float rb[4][2];
    __shared__ unsigned sdone;
    if (lane == 0) { rb[widx][0] = num; rb[widx][1] = den; }
    __syncthreads();
    if (x == 0) {
        const float fn = rb[0][0] + rb[1][0] + rb[2][0] + rb[3][0];
        const float fd = rb[0][1] + rb[1][1] + rb[2][1] + rb[3][1];
        float2* nd2 = (float2*)(ws + WS_ND_);
        nd2[k * 64 + b * 4 + sg] = make_float2(fn, fd);   // grouped by class
        __threadfence();                                   // release partial
        sdone = atomicAdd((unsigned*)(ws + WS_CNT_), 1u);
    }
    __syncthreads();
    if (sdone == (unsigned)(NBLK_FUSED_ - 1)) {           // last block finalizes
        __threadfence();                                   // acquire partials
        if (x < 64) {
            float term = 0.f;
            if (x < K_) {
                const float2* nd2 = (const float2*)(ws + WS_ND_);
                float ns = 0.f, ds = 0.f;
                for (int i = 0; i < 64; ++i) {
                    const float2 v = nd2[x * 64 + i];
                    ns += v.x; ds += v.y;
                }
                term = fabsf(ns / (ds + 1e-6f));
            }
            for (int o = 32; o > 0; o >>= 1) term += __shfl_down(term, o);
            if (x == 0) out[0] = (float)K_ - term;
        }
    }
}

extern "C" void kernel_launch(void* const* d_in, const int* in_sizes, int n_in,
                              void* d_out, int out_size, void* d_ws, size_t ws_size,
                              hipStream_t stream) {
    const float* labels = (const float*)d_in[0];
    const float* inputs = (const float*)d_in[1];
    float* ws = (float*)d_ws;   // needs WS_CNT_+1 floats ~= 31 KB

    stats_k<<<dim3(SCH_, K_ / KT_, B_), 256, 0, stream>>>(labels, inputs, ws);
    fused_k<<<dim3(4, K_, B_), 256, 0, stream>>>(labels, inputs, ws, (float*)d_out);
}